// Round 8
// baseline (630.372 us; speedup 1.0000x reference)
//
#include <hip/hip_runtime.h>
#include <hip/hip_bf16.h>
#include <math.h>

#define HH    4
#define NSEQ  1024
#define KVD   960    // true KV dim
#define KVP   1024   // padded KV dim (zero pad) so every tile dim is 128-divisible
#define BATCH 8
#define ECAT  1024   // concat of branch channel dims (960 real, 64 pad rows)

static constexpr float EPS = 1e-5f;

typedef __attribute__((ext_vector_type(8))) short short8;   // 8 bf16
typedef __attribute__((ext_vector_type(4))) short short4e;  // 4 bf16
typedef __attribute__((ext_vector_type(4))) float f32x4;    // MFMA C/D frag

__device__ __forceinline__ short f2bf(float x) {
    union { __hip_bfloat16 h; short s; } u;
    u.h = __float2bfloat16(x);
    return u.s;
}
__device__ __forceinline__ short8 cvt8(const float* __restrict__ g) {
    const float4 a = *(const float4*)g;
    const float4 b = *(const float4*)(g + 4);
    short8 t;
    t[0] = f2bf(a.x); t[1] = f2bf(a.y); t[2] = f2bf(a.z); t[3] = f2bf(a.w);
    t[4] = f2bf(b.x); t[5] = f2bf(b.y); t[6] = f2bf(b.z); t[7] = f2bf(b.w);
    return t;
}

// ---- one-time input converts: 15 segments (13 plain + 2 padded-W) in ONE launch
struct ConvJobs {
    const float* src[15];
    short*       dst[15];
    long         cum[16];
    int          type[15];   // 0 = plain copy, 1 = padded WK/WV layout
    float*       statsAcc;   // zero-init side effect (block 0)
    int          nAcc;
};

__global__ void conv_all_kernel(ConvJobs J)
{
    if (blockIdx.x == 0 && threadIdx.x < (unsigned)J.nAcc)
        J.statsAcc[threadIdx.x] = 0.f;
    const long u = (long)blockIdx.x * 256 + threadIdx.x;
    if (u >= J.cum[15]) return;
    int sg = 0;
    while (u >= J.cum[sg + 1]) ++sg;
    const long l = u - J.cum[sg];
    if (J.type[sg] == 0) {
        *(short8*)(J.dst[sg] + l * 8) = cvt8(J.src[sg] + l * 8);
    } else {
        const int cpr = KVD / 8;                              // 120
        const int c8  = (int)(l % cpr) * 8;
        const int row = (int)((l / cpr) % KVP);
        const int h   = (int)(l / ((long)cpr * KVP));
        short8 t = (short8){0,0,0,0,0,0,0,0};
        if (row < KVD) t = cvt8(J.src[sg] + ((long)h * KVD + row) * KVD + c8);
        *(short8*)(J.dst[sg] + ((long)h * KVP + row) * KVD + c8) = t;
    }
}

// ---- legacy async LDS staging: ROWS x 32 bf16, 64B rows, chunk-XOR swizzle.
template<int ROWS>
__device__ __forceinline__ void stage_async(short (*dst)[32], const short* __restrict__ src,
                                            int ld, int w, int lane)
{
    #pragma unroll
    for (int p = 0; p < ROWS / 64; ++p) {
        const int rbase = p * 64 + w * 16;
        const int row   = rbase + (lane >> 2);
        const int c16l  = ((lane & 3) - row) & 3;
        const short* g  = src + (long)row * ld + c16l * 8;
        __builtin_amdgcn_global_load_lds(
            (const __attribute__((address_space(1))) void*)g,
            (__attribute__((address_space(3))) void*)&dst[rbase][0],
            16, 0, 0);
    }
}

// ---------------------------------------------------------------------------
struct GemmJob {
    const short* A; const short* B; void* C;
    float alpha;
    int lda, ldb, ldc, K, inner, gx, gy, Z, splitH, cfg, blkBase, cfloat;
    long sA, sB, zAh, zAg, zBh, zBg, zCh, zCg;
};
struct GemmJobs { GemmJob j[8]; int njobs; };

// ---- legacy 128^2 GEMM body (verified): C = alpha * sum_ib A[M,K] @ B[Nc,K]^T
// Output type is per-job runtime (cfloat): enables mixing bf16-out Q jobs with
// f32-out O jobs in ONE dispatch (epilogue-only branch).
template<int TM, int TN>
__device__ __forceinline__ void gemm_body(const GemmJob& job, int lb,
                                          short (*As)[32], short (*Bs)[32])
{
    constexpr int MT = TM / 32;
    constexpr int NT = TN / 32;
    const short* A = job.A;
    const short* B = job.B;
    const int bps = job.gx * job.gy;
    const int Z   = job.Z;
    int z, r;
    if ((Z & 7) == 0) {
        const int xcd = lb & 7;
        const int j   = lb >> 3;
        const int spx = Z >> 3;
        z = xcd * spx + j / bps;
        r = j % bps;
    } else {
        z = lb / bps;
        r = lb % bps;
    }
    const int x = r % job.gx, y = r / job.gx;
    int h, g;
    if (job.splitH) { h = z & (HH - 1); g = z >> 2; }
    else            { h = 0;            g = z;      }
    A += (long)h * job.zAh + (long)g * job.zAg;
    B += (long)h * job.zBh + (long)g * job.zBg;
    const int esz = job.cfloat ? 4 : 2;
    char* Cb = (char*)job.C + ((long)h * job.zCh + (long)g * job.zCg) * esz;

    const int tid  = threadIdx.x;
    const int lane = tid & 63;
    const int w    = tid >> 6;
    const int wr   = w >> 1;
    const int wc   = w & 1;
    const int quad = lane >> 4;
    const int l16  = lane & 15;
    const long m0  = (long)y * TM;
    const long n0  = (long)x * TN;

    f32x4 acc[MT][NT];
    #pragma unroll
    for (int i = 0; i < MT; ++i)
        #pragma unroll
        for (int j2 = 0; j2 < NT; ++j2)
            acc[i][j2] = (f32x4){0.f, 0.f, 0.f, 0.f};

    for (int ib = 0; ib < job.inner; ++ib) {
        const short* Ab = A + (long)ib * job.sA + m0 * job.lda;
        const short* Bb = B + (long)ib * job.sB + n0 * job.ldb;
        for (int k0 = 0; k0 < job.K; k0 += 32) {
            stage_async<TM>(As, Ab + k0, job.lda, w, lane);
            stage_async<TN>(Bs, Bb + k0, job.ldb, w, lane);
            __syncthreads();
            short8 af[MT], bfr[NT];
            #pragma unroll
            for (int i = 0; i < MT; ++i) {
                const int rowA = wr * (TM / 2) + i * 16 + l16;
                af[i] = *(const short8*)&As[rowA][((quad + rowA) & 3) * 8];
            }
            #pragma unroll
            for (int j2 = 0; j2 < NT; ++j2) {
                const int rowB = wc * (TN / 2) + j2 * 16 + l16;
                bfr[j2] = *(const short8*)&Bs[rowB][((quad + rowB) & 3) * 8];
            }
            #pragma unroll
            for (int i = 0; i < MT; ++i)
                #pragma unroll
                for (int j2 = 0; j2 < NT; ++j2)
                    acc[i][j2] = __builtin_amdgcn_mfma_f32_16x16x32_bf16(
                        af[i], bfr[j2], acc[i][j2], 0, 0, 0);
            __syncthreads();
        }
    }

    #pragma unroll
    for (int i = 0; i < MT; ++i) {
        #pragma unroll
        for (int j2 = 0; j2 < NT; ++j2) {
            const long row = m0 + wr * (TM / 2) + i * 16 + quad * 4;
            const long col = n0 + wc * (TN / 2) + j2 * 16 + l16;
            #pragma unroll
            for (int rr = 0; rr < 4; ++rr) {
                const float v = job.alpha * acc[i][j2][rr];
                const long idx = (row + rr) * job.ldc + col;
                if (job.cfloat) ((float*)Cb)[idx] = v;
                else            ((short*)Cb)[idx] = f2bf(v);
            }
        }
    }
}

__global__ __launch_bounds__(256) void mfma_jt(GemmJobs J)
{
    __shared__ short As[128][32];
    __shared__ short Bs[128][32];
    const int bid = blockIdx.x;
    int ji = 0;
    while (ji + 1 < J.njobs && bid >= J.j[ji + 1].blkBase) ++ji;
    const GemmJob& job = J.j[ji];
    const int lb = bid - job.blkBase;
    switch (job.cfg) {
        case 0: gemm_body<128, 128>(job, lb, As, Bs); break;
        case 1: gemm_body<128,  64>(job, lb, As, Bs); break;
        default: gemm_body<64, 128>(job, lb, As, Bs); break;
    }
}

// ---------------------------------------------------------------------------
// 256^2-tile, BK=64, 8-wave bf16 NT GEMM, counted vmcnt/lgkmcnt.
// TWO verified schedules, selected per-dispatch (both passed refcheck in
// earlier rounds; measured: SCHED=0 best for the mixed-NT mega1 dispatch,
// SCHED=1 best for the uniform NT=16 S/Ch dispatches):
//   SCHED=0 (round-6): 4 phases/tile, B panel cached once (24 ds_reads),
//            stages ph1:(t+1)A1 ph2:(t+1)B1 ph3:(t+2)A0 ph4:(t+2)B0+vmcnt(4)
//   SCHED=1 (round-7): 1 barrier-pair/tile, 24 reads up-front, lgkmcnt(8)
//            mid-barrier, MFMA(A0,B) covers A1 drain, vmcnt(4) at tile end
// ---------------------------------------------------------------------------
#define STAGE(Pa, Pb, DST) do {                                                  \
    __builtin_amdgcn_global_load_lds(                                            \
        (const __attribute__((address_space(1))) void*)(Pa),                     \
        (__attribute__((address_space(3))) void*)(DST), 16, 0, 0);               \
    __builtin_amdgcn_global_load_lds(                                            \
        (const __attribute__((address_space(1))) void*)(Pb),                     \
        (__attribute__((address_space(3))) void*)((DST) + 4096), 16, 0, 0);      \
    (Pa) += 64; (Pb) += 64;                                                      \
} while (0)

// ---- SCHED=0 pieces (round-6) ----------------------------------------------
#define S6_BARRQ(AA, BB) do {                                                    \
    __builtin_amdgcn_s_barrier();                                                \
    asm volatile("s_waitcnt lgkmcnt(0)" ::: "memory");                           \
    __builtin_amdgcn_sched_barrier(0);                                           \
    __builtin_amdgcn_s_setprio(1);                                               \
    _Pragma("unroll")                                                            \
    for (int mi_ = 0; mi_ < 4; ++mi_)                                            \
        _Pragma("unroll")                                                        \
        for (int nj_ = 0; nj_ < 2; ++nj_) {                                      \
            acc[(AA)*4 + mi_][(BB)*2 + nj_] = __builtin_amdgcn_mfma_f32_16x16x32_bf16( \
                af_[mi_][0], bfall_[(BB)*2 + nj_][0],                            \
                acc[(AA)*4 + mi_][(BB)*2 + nj_], 0, 0, 0);                       \
            acc[(AA)*4 + mi_][(BB)*2 + nj_] = __builtin_amdgcn_mfma_f32_16x16x32_bf16( \
                af_[mi_][1], bfall_[(BB)*2 + nj_][1],                            \
                acc[(AA)*4 + mi_][(BB)*2 + nj_], 0, 0, 0);                       \
        }                                                                        \
    __builtin_amdgcn_s_setprio(0);                                               \
    __builtin_amdgcn_s_barrier();                                                \
} while (0)

#define S6_TILE(Q, T) do {                                                       \
    short8 af_[4][2], bfall_[4][2];                                              \
    _Pragma("unroll")                                                            \
    for (int mi_ = 0; mi_ < 4; ++mi_)                                            \
        _Pragma("unroll")                                                        \
        for (int ks_ = 0; ks_ < 2; ++ks_)                                        \
            af_[mi_][ks_] = *(const short8*)(paf0[mi_][ks_] + (Q)*16384);        \
    _Pragma("unroll")                                                            \
    for (int nj_ = 0; nj_ < 4; ++nj_)                                            \
        _Pragma("unroll")                                                        \
        for (int ks_ = 0; ks_ < 2; ++ks_)                                        \
            bfall_[nj_][ks_] = *(const short8*)(pbf0[nj_][ks_] + (Q)*16384);     \
    if ((T) + 1 < NT) STAGE(gA1a, gA1b, &AT[1-(Q)][1][0][0] + dofs);             \
    asm volatile("s_waitcnt lgkmcnt(8)" ::: "memory");                           \
    S6_BARRQ(0, 0);                                                              \
    if ((T) + 1 < NT) STAGE(gB1a, gB1b, &BT[1-(Q)][1][0][0] + dofs);             \
    S6_BARRQ(0, 1);                                                              \
    _Pragma("unroll")                                                            \
    for (int mi_ = 0; mi_ < 4; ++mi_)                                            \
        _Pragma("unroll")                                                        \
        for (int ks_ = 0; ks_ < 2; ++ks_)                                        \
            af_[mi_][ks_] = *(const short8*)(paf0[mi_][ks_] + (Q)*16384 + 8192); \
    if ((T) + 2 < NT) STAGE(gA0a, gA0b, &AT[(Q)][0][0][0] + dofs);               \
    S6_BARRQ(1, 0);                                                              \
    if ((T) + 2 < NT) {                                                          \
        STAGE(gB0a, gB0b, &BT[(Q)][0][0][0] + dofs);                             \
        asm volatile("s_waitcnt vmcnt(4)" ::: "memory");                         \
    } else {                                                                     \
        asm volatile("s_waitcnt vmcnt(0)" ::: "memory");                         \
    }                                                                            \
    S6_BARRQ(1, 1);                                                              \
} while (0)

// ---- SCHED=1 pieces (round-7) ----------------------------------------------
#define S7_MFMAQ(AF, AA)                                                         \
    _Pragma("unroll")                                                            \
    for (int mi_ = 0; mi_ < 4; ++mi_)                                            \
        _Pragma("unroll")                                                        \
        for (int nj_ = 0; nj_ < 4; ++nj_) {                                      \
            acc[(AA)*4 + mi_][nj_] = __builtin_amdgcn_mfma_f32_16x16x32_bf16(    \
                AF[mi_][0], ball_[nj_][0], acc[(AA)*4 + mi_][nj_], 0, 0, 0);     \
            acc[(AA)*4 + mi_][nj_] = __builtin_amdgcn_mfma_f32_16x16x32_bf16(    \
                AF[mi_][1], ball_[nj_][1], acc[(AA)*4 + mi_][nj_], 0, 0, 0);     \
        }

#define S7_TILE(Q, T) do {                                                       \
    short8 af0_[4][2], af1_[4][2], ball_[4][2];                                  \
    _Pragma("unroll")                                                            \
    for (int nj_ = 0; nj_ < 4; ++nj_)                                            \
        _Pragma("unroll")                                                        \
        for (int ks_ = 0; ks_ < 2; ++ks_)                                        \
            ball_[nj_][ks_] = *(const short8*)(pbf0[nj_][ks_] + (Q)*16384);      \
    _Pragma("unroll")                                                            \
    for (int mi_ = 0; mi_ < 4; ++mi_)                                            \
        _Pragma("unroll")                                                        \
        for (int ks_ = 0; ks_ < 2; ++ks_)                                        \
            af0_[mi_][ks_] = *(const short8*)(paf0[mi_][ks_] + (Q)*16384);       \
    _Pragma("unroll")                                                            \
    for (int mi_ = 0; mi_ < 4; ++mi_)                                            \
        _Pragma("unroll")                                                        \
        for (int ks_ = 0; ks_ < 2; ++ks_)                                        \
            af1_[mi_][ks_] = *(const short8*)(paf0[mi_][ks_] + (Q)*16384 + 8192);\
    if ((T) + 1 < NT) {                                                          \
        STAGE(gA1a, gA1b, &AT[1-(Q)][1][0][0] + dofs);                           \
        STAGE(gB1a, gB1b, &BT[1-(Q)][1][0][0] + dofs);                           \
    }                                                                            \
    asm volatile("s_waitcnt lgkmcnt(8)" ::: "memory");                           \
    __builtin_amdgcn_s_barrier();                                                \
    if ((T) + 2 < NT) {                                                          \
        STAGE(gA0a, gA0b, &AT[(Q)][0][0][0] + dofs);                             \
        STAGE(gB0a, gB0b, &BT[(Q)][0][0][0] + dofs);                             \
    }                                                                            \
    __builtin_amdgcn_sched_barrier(0);                                           \
    __builtin_amdgcn_s_setprio(1);                                               \
    S7_MFMAQ(af0_, 0);                                                           \
    __builtin_amdgcn_s_setprio(0);                                               \
    asm volatile("s_waitcnt lgkmcnt(0)" ::: "memory");                           \
    __builtin_amdgcn_sched_barrier(0);                                           \
    __builtin_amdgcn_s_setprio(1);                                               \
    S7_MFMAQ(af1_, 1);                                                           \
    __builtin_amdgcn_s_setprio(0);                                               \
    if ((T) + 2 < NT) asm volatile("s_waitcnt vmcnt(4)" ::: "memory");           \
    else              asm volatile("s_waitcnt vmcnt(0)" ::: "memory");           \
    __builtin_amdgcn_s_barrier();                                                \
} while (0)

template<typename TC, int STATS, int SCHED>
__global__ __launch_bounds__(512, 2) void mfma8(GemmJobs J, float* __restrict__ statsAcc)
{
    __shared__ short AT[2][2][128][64];
    __shared__ short BT[2][2][128][64];

    const int bid = blockIdx.x;
    int ji = 0;
    while (ji + 1 < J.njobs && bid >= J.j[ji + 1].blkBase) ++ji;
    const GemmJob& job = J.j[ji];
    const int lb = bid - job.blkBase;
    const int Z  = job.Z;
    const int gx = job.gx;
    const int bps = gx * job.gy;
    int z, r;
    if ((Z & 7) == 0) {
        const int xcd = lb & 7;
        const int jj  = lb >> 3;
        const int spx = Z >> 3;
        z = xcd * spx + jj / bps;
        r = jj % bps;
    } else {
        z = lb / bps;
        r = lb % bps;
    }
    const int x = r % gx, y = r / gx;
    int h, g;
    if (job.splitH) { h = z & (HH - 1); g = z >> 2; }
    else            { h = 0;            g = z;      }
    const int lda = job.lda, ldb = job.ldb, ldc = job.ldc;
    const short* A = job.A + (long)h * job.zAh + (long)g * job.zAg + (long)(y * 256) * lda;
    const short* B = job.B + (long)h * job.zBh + (long)g * job.zBg + (long)(x * 256) * ldb;
    TC* C = (TC*)job.C + (long)h * job.zCh + (long)g * job.zCg;
    const int NT = job.K >> 6;

    const int tid  = threadIdx.x;
    const int lane = tid & 63;
    const int w    = tid >> 6;
    const int wm   = w >> 2;        // 0..1
    const int wn   = w & 3;         // 0..3
    const int quad = lane >> 4;
    const int l16  = lane & 15;
    const int dofs = w * 512;       // LDS short-offset of this wave's 1KB stage slot

    // global stage pointers (per-lane, chunk-rotation pre-swizzled [m104/m173])
    const int o16 = w * 64 + lane;
    const int rS  = o16 >> 3;
    const int pcS = o16 & 7;
    const int lcS = ((pcS - rS) & 7) * 8;
    const short* gA0a = A + (long)rS * lda + lcS;
    const short* gA0b = A + (long)(rS + 64) * lda + lcS;
    const short* gA1a = gA0a + 128 * lda;
    const short* gA1b = gA0b + 128 * lda;
    const short* gB0a = B + (long)rS * ldb + lcS;
    const short* gB0b = B + (long)(rS + 64) * ldb + lcS;
    const short* gB1a = gB0a + 128 * ldb;
    const short* gB1b = gB0b + 128 * ldb;

    // hoisted LDS fragment base addresses (q=0; A at half0, B covers both halves)
    const short* paf0[4][2];
    #pragma unroll
    for (int mi = 0; mi < 4; ++mi)
        #pragma unroll
        for (int ks = 0; ks < 2; ++ks) {
            const int rr = mi * 32 + wm * 16 + l16;
            paf0[mi][ks] = &AT[0][0][rr][((ks * 4 + quad + rr) & 7) * 8];
        }
    const short* pbf0[4][2];
    #pragma unroll
    for (int nj = 0; nj < 4; ++nj)
        #pragma unroll
        for (int ks = 0; ks < 2; ++ks) {
            const int r2 = (nj & 1) * 64 + wn * 16 + l16;
            pbf0[nj][ks] = &BT[0][nj >> 1][r2][((ks * 4 + quad + r2) & 7) * 8];
        }

    f32x4 acc[8][4];
    #pragma unroll
    for (int i = 0; i < 8; ++i)
        #pragma unroll
        for (int j2 = 0; j2 < 4; ++j2)
            acc[i][j2] = (f32x4){0.f, 0.f, 0.f, 0.f};

    // prologue: tile0 all 4 halves + tile1 A0/B0; drain tile0, keep tile1 in flight
    STAGE(gA0a, gA0b, &AT[0][0][0][0] + dofs);
    STAGE(gA1a, gA1b, &AT[0][1][0][0] + dofs);
    STAGE(gB0a, gB0b, &BT[0][0][0][0] + dofs);
    STAGE(gB1a, gB1b, &BT[0][1][0][0] + dofs);
    STAGE(gA0a, gA0b, &AT[1][0][0][0] + dofs);   // NT >= 4 in all uses
    STAGE(gB0a, gB0b, &BT[1][0][0][0] + dofs);
    asm volatile("s_waitcnt vmcnt(4)" ::: "memory");
    __builtin_amdgcn_s_barrier();

    const int NPAIR = NT >> 1;
    if constexpr (SCHED == 0) {
        for (int tt = 0; tt < NPAIR; ++tt) {
            S6_TILE(0, tt * 2);
            S6_TILE(1, tt * 2 + 1);
        }
        if (NT & 1) S6_TILE(0, NT - 1);
    } else {
        for (int tt = 0; tt < NPAIR; ++tt) {
            S7_TILE(0, tt * 2);
            S7_TILE(1, tt * 2 + 1);
        }
        if (NT & 1) S7_TILE(0, NT - 1);
    }

    // epilogue: C/D layout col=lane&15, row=(lane>>4)*4+reg [m89-verified]
    float s0 = 0.f, ss0 = 0.f, s1 = 0.f, ss1 = 0.f;   // buckets: rows<896, rows 896..959
    #pragma unroll
    for (int mi = 0; mi < 8; ++mi) {
        #pragma unroll
        for (int nj = 0; nj < 4; ++nj) {
            const long row = (long)y * 256 + mi * 32 + wm * 16 + quad * 4;
            const long col = (long)x * 256 + nj * 64 + wn * 16 + l16;
            #pragma unroll
            for (int rr = 0; rr < 4; ++rr) {
                const float v = job.alpha * acc[mi][nj][rr];
                if constexpr (sizeof(TC) == 4)
                    C[(row + rr) * ldc + col] = v;
                else
                    C[(row + rr) * ldc + col] = f2bf(v);
                if constexpr (STATS) {
                    const long gr = row + rr;
                    if (gr < 896)          { s0 += v; ss0 += v * v; }
                    else if (gr < KVD)     { s1 += v; ss1 += v * v; }
                }
            }
        }
    }
    if constexpr (STATS) {
        __syncthreads();
        float* red = (float*)&AT[0][0][0][0];
        red[tid] = s0; red[512 + tid] = ss0; red[1024 + tid] = s1; red[1536 + tid] = ss1;
        __syncthreads();
        for (int o = 256; o > 0; o >>= 1) {
            if (tid < o) {
                red[tid]        += red[tid + o];
                red[512 + tid]  += red[512 + tid + o];
                red[1024 + tid] += red[1024 + tid + o];
                red[1536 + tid] += red[1536 + tid + o];
            }
            __syncthreads();
        }
        if (tid == 0) {
            const int m0g = y * 256;
            const int bA = (m0g >= 768) ? 1 : (m0g >= 512) ? 2 : 3;
            atomicAdd(&statsAcc[((long)z * 4 + bA) * 2],     red[0]);
            atomicAdd(&statsAcc[((long)z * 4 + bA) * 2 + 1], red[512]);
            if (y == 3) {   // rows 896..959 -> branch 0 (df=64)
                atomicAdd(&statsAcc[((long)z * 4 + 0) * 2],     red[1024]);
                atomicAdd(&statsAcc[((long)z * 4 + 0) * 2 + 1], red[1536]);
            }
        }
    }
}

// ---- softmax over real 960 cols; stats finalize inlined (reads atomic sums).
__global__ void softmax_kernel(const float* __restrict__ S,
                               short* __restrict__ Sa,
                               const float* __restrict__ acc)
{
    const int row = blockIdx.x;          // 0..1023 concat rows (>=960 = pad)
    const int y   = blockIdx.y;
    const int t   = threadIdx.x;
    short* orow = Sa + ((long)y * ECAT + row) * KVP;
    if (row >= KVD) {                    // zero pad row (clean B-operand for Ch)
        *(short4e*)(orow + 4 * t) = (short4e){0, 0, 0, 0};
        return;
    }
    const int bidx = (row >= 896) ? 0 : (row >= 768) ? 1 : (row >= 512) ? 2 : 3;
    const int dftab[4] = {64, 128, 256, 512};
    const float sum0 = acc[((long)y * 4 + bidx) * 2];
    const float ssq0 = acc[((long)y * 4 + bidx) * 2 + 1];
    const float n    = (float)(dftab[bidx] * KVD);
    const float mean = sum0 / n;
    const float rstd = rsqrtf(ssq0 / n - mean * mean + EPS);
    const float* srow = S + ((long)y * ECAT + row) * KVP;

    const bool real = (t < KVD / 4);     // threads 0..239 hold real cols (4 each)
    float x[4];
    float mx = -1e30f;
    if (real) {
        const float4 v = *(const float4*)(srow + 4 * t);
        x[0] = (v.x - mean) * rstd; x[1] = (v.y - mean) * rstd;
        x[2] = (v.z - mean) * rstd; x[3] = (v.w - mean) * rstd;
        mx = fmaxf(fmaxf(x[0], x[1]), fmaxf(x[2], x[3]));
    }
    __shared__ float red[256];
    red[t] = mx; __syncthreads();
    for (int o = 128; o > 0; o >>= 1) {
        if (t < o) red[t] = fmaxf(red[t], red[t + o]);
        __syncthreads();
    }
    mx = red[0];
    __syncthreads();

    float e[4] = {0.f, 0.f, 0.f, 0.f};
    float sum = 0.f;
    if (real) {
        e[0] = __expf(x[0] - mx); e[1] = __expf(x[1] - mx);
        e[2] = __expf(x[2] - mx); e[3] = __expf(x[3] - mx);
        sum = e[0] + e[1] + e[2] + e[3];
    }
    red[t] = sum; __syncthreads();
    for (int o = 128; o > 0; o >>= 1) {
        if (t < o) red[t] += red[t + o];
        __syncthreads();
    }
    const float inv = 1.0f / red[0];
    short4e o4;
    o4[0] = f2bf(e[0] * inv); o4[1] = f2bf(e[1] * inv);
    o4[2] = f2bf(e[2] * inv); o4[3] = f2bf(e[3] * inv);
    *(short4e*)(orow + 4 * t) = o4;
}

// ---------------------------------------------------------------------------
extern "C" void kernel_launch(void* const* d_in, const int* in_sizes, int n_in,
                              void* d_out, int out_size, void* d_ws, size_t ws_size,
                              hipStream_t stream)
{
    (void)in_sizes; (void)n_in; (void)out_size;
    const float* emb[4]  = {(const float*)d_in[0], (const float*)d_in[1],
                            (const float*)d_in[2], (const float*)d_in[3]};
    const float* emb_all = (const float*)d_in[4];
    const float* WQ[4]   = {(const float*)d_in[5], (const float*)d_in[6],
                            (const float*)d_in[7], (const float*)d_in[8]};
    const float* WK      = (const float*)d_in[9];
    const float* WV      = (const float*)d_in[10];
    const float* WO[4]   = {(const float*)d_in[11], (const float*)d_in[12],
                            (const float*)d_in[13], (const float*)d_in[14]};
    float* out = (float*)d_out;

    const int dfs[4]    = {64, 128, 256, 512};
    const int rowoff[4] = {896, 768, 512, 0};   // concat offsets (tile-aligned)
    const long N = NSEQ;

    // ---- workspace budget (Sacat aliases KT+Qcat; Chcat aliases Scat)
    const long eAll = (long)BATCH * N * KVD;
    const long eWKp = (long)HH * KVP * KVD;
    long preBytes = eAll * 2 + 2 * eWKp * 2;
    for (int br = 0; br < 4; ++br)
        preBytes += ((long)BATCH * N * dfs[br] + (long)HH * dfs[br] * dfs[br]
                    + (long)dfs[br] * dfs[br]) * 2;
    const long perG = (long)HH * KVP * N * 2
                    + (long)HH * ECAT * N * 2
                    + (long)HH * N * KVP * 2
                    + (long)HH * ECAT * KVP * 4;
    int G = 8;
    while (G > 1 && preBytes + (long)G * perG + 65536 > (long)ws_size) G >>= 1;

    // ---- carve workspace (KTb and Qb contiguous: Sab aliases their union)
    char* p = (char*)d_ws;
    short* embAllp = (short*)p; p += eAll * 2;
    short* embp[4]; short* WQp[4]; short* WOp[4];
    for (int br = 0; br < 4; ++br) { embp[br] = (short*)p; p += (long)BATCH * N * dfs[br] * 2; }
    for (int br = 0; br < 4; ++br) { WQp[br]  = (short*)p; p += (long)HH * dfs[br] * dfs[br] * 2; }
    short* WKp = (short*)p; p += eWKp * 2;
    short* WVp = (short*)p; p += eWKp * 2;
    for (int br = 0; br < 4; ++br) { WOp[br]  = (short*)p; p += (long)dfs[br] * dfs[br] * 2; }
    short* KTb = (short*)p; p += (long)G * HH * KVP * N * 2;
    short* Qb  = (short*)p; p += (long)G * HH * ECAT * N * 2;    // Qcat
    short* Vb  = (short*)p; p += (long)G * HH * N * KVP * 2;
    float* Sb  = (float*)p; p += (long)G * HH * ECAT * KVP * 4;  // Scat
    float* statsAcc = (float*)p; p += (long)BATCH * HH * 4 * 2 * 4;
    short* Sab = (short*)KTb;  // Sacat aliases KT+Qcat (dead after S GEMM)
    short* Chb = (short*)Sb;   // Chcat aliases Scat (dead after softmax)

    // ---- ONE convert launch: 13 plain segments + 2 padded-W segments
    {
        ConvJobs J;
        long cum = 0; int sg = 0;
        auto addJob = [&](const float* src, short* dst, long nunits, int ty) {
            J.src[sg] = src; J.dst[sg] = dst; J.cum[sg] = cum; J.type[sg] = ty;
            cum += nunits; ++sg;
        };
        addJob(emb_all, embAllp, eAll / 8, 0);
        for (int br = 0; br < 4; ++br) addJob(emb[br], embp[br], (long)BATCH * N * dfs[br] / 8, 0);
        for (int br = 0; br < 4; ++br) addJob(WQ[br], WQp[br], (long)HH * dfs[br] * dfs[br] / 8, 0);
        for (int br = 0; br < 4; ++br) addJob(WO[br], WOp[br], (long)dfs[br] * dfs[br] / 8, 0);
        addJob(WK, WKp, (long)HH * KVP * (KVD / 8), 1);
        addJob(WV, WVp, (long)HH * KVP * (KVD / 8), 1);
        J.cum[15] = cum;
        J.statsAcc = statsAcc;
        J.nAcc = BATCH * HH * 4 * 2;
        conv_all_kernel<<<dim3((unsigned)((cum + 255) / 256)), dim3(256), 0, stream>>>(J);
    }

    const float scale = 1.0f / sqrtf((float)KVD);
    long outBase[4];
    {
        long acc = 0;
        for (int br = 0; br < 4; ++br) { outBase[br] = acc; acc += (long)BATCH * N * dfs[br]; }
    }

    // builds the 4 O-branch jobs for a given b0 into J starting at *base
    auto addOJobs = [&](GemmJobs& J, int& nj, int& base, int b0, int G_) {
        for (int br = 3; br >= 0; --br) {
            const int df = dfs[br];
            GemmJob& q = J.j[nj];
            q.A = Chb + rowoff[br]; q.B = WOp[br];
            q.C = out + outBase[br] + (long)b0 * N * df;
            q.alpha = 1.0f / HH; q.cfloat = 1;
            q.lda = ECAT; q.ldb = df; q.ldc = df; q.K = df; q.inner = HH;
            q.sA = (long)N * ECAT; q.sB = 0;
            q.zAh = 0; q.zAg = (long)HH * N * ECAT; q.zBh = 0; q.zBg = 0;
            q.zCh = 0; q.zCg = (long)N * df;
            q.splitH = 0; q.Z = G_; q.gy = 8;
            if (df >= 128) { q.cfg = 0; q.gx = df / 128; }
            else           { q.cfg = 1; q.gx = 1;        }
            q.blkBase = base;
            base += q.gx * q.gy * G_;
            ++nj;
        }
    };

    const dim3 blk(256), blk8(512);
    int it = 0;
    int prevB0 = -1;
    for (int b0 = 0; b0 < BATCH; b0 += G, ++it) {
        const int Z = G * HH;
        const short* embA = embAllp + (long)b0 * N * KVD;
        float* accIt = statsAcc + (long)it * Z * 4 * 2;

        // ---- mega1 on mfma8 SCHED=0: KT + V + Q512 + Q256 ---------------------
        {
            GemmJobs J; int nj = 0; int base = 0;
            auto add8 = [&](const short* A, const short* B, void* C, float alpha,
                            int lda, int ldb, int ldc, int K,
                            long zAh, long zAg, long zBh, long zBg,
                            long zCh, long zCg, int gx, int gy) {
                GemmJob& q = J.j[nj];
                q.A = A; q.B = B; q.C = C; q.alpha = alpha; q.cfloat = 0;
                q.lda = lda; q.ldb = ldb; q.ldc = ldc; q.K = K; q.inner = 1;
                q.sA = 0; q.sB = 0;
                q.zAh = zAh; q.zAg = zAg; q.zBh = zBh; q.zBg = zBg;
                q.zCh = zCh; q.zCg = zCg;
                q.splitH = 1; q.gx = gx; q.gy = gy; q.Z = Z; q.cfg = 0;
                q.blkBase = base;
                base += gx * gy * Z; ++nj;
            };
            add8(WKp, embA, KTb, 1.0f, KVD, KVD, (int)N, KVD,
                 (long)KVP * KVD, 0, 0, (long)N * KVD,
                 (long)KVP * N, (long)HH * KVP * N, 4, 4);
            add8(embA, WVp, Vb, 1.0f, KVD, KVD, KVP, KVD,
                 0, (long)N * KVD, (long)KVP * KVD, 0,
                 (long)N * KVP, (long)HH * N * KVP, 4, 4);
            add8(WQp[3], embp[3] + (long)b0 * N * 512, Qb + (long)rowoff[3] * N, 1.0f,
                 512, 512, (int)N, 512,
                 512L * 512, 0, 0, (long)N * 512,
                 (long)ECAT * N, (long)HH * ECAT * N, 4, 2);
            add8(WQp[2], embp[2] + (long)b0 * N * 256, Qb + (long)rowoff[2] * N, 1.0f,
                 256, 256, (int)N, 256,
                 256L * 256, 0, 0, (long)N * 256,
                 (long)ECAT * N, (long)HH * ECAT * N, 4, 1);
            J.njobs = nj;
            mfma8<short, 0, 0><<<dim3(base), blk8, 0, stream>>>(J, nullptr);
        }

        // ---- legacy dispatch: Q128 + Q64 (this iter) + O (previous iter) ------
        // O(prev) reads Chb (alias of Sb) and MUST complete before S overwrites
        // Sb below — guaranteed by in-stream ordering.
        {
            GemmJobs J; int nj = 0; int base = 0;
            for (int br = 1; br >= 0; --br) {
                const int df = dfs[br];
                GemmJob& q = J.j[nj];
                q.A = WQp[br]; q.B = embp[br] + (long)b0 * N * df;
                q.C = Qb + (long)rowoff[br] * N;
                q.alpha = 1.0f; q.cfloat = 0;
                q.lda = df; q.ldb = df; q.ldc = (int)N; q.K = df; q.inner = 1;
                q.sA = 0; q.sB = 0;
                q.zAh = (long)df * df; q.zAg = 0;
                q.zBh = 0;             q.zBg = (long)N * df;
                q.zCh = (long)ECAT * N; q.zCg = (long)HH * ECAT * N;
                q.splitH = 1; q.Z = Z; q.gx = 8; q.gy = 1;
                q.cfg = (df >= 128) ? 0 : 2;
                q.blkBase = base;
                base += 8 * Z;
                ++nj;
            }
            if (prevB0 >= 0) addOJobs(J, nj, base, prevB0, G);
            J.njobs = nj;
            mfma_jt<<<dim3(base), blk, 0, stream>>>(J);
        }

        // ---- S on mfma8 SCHED=1 (fused instance-norm stats) -------------------
        {
            GemmJobs J; J.njobs = 1;
            GemmJob& s = J.j[0];
            s.A = Qb; s.B = KTb; s.C = Sb; s.alpha = scale; s.cfloat = 1;
            s.lda = (int)N; s.ldb = (int)N; s.ldc = KVP; s.K = (int)N; s.inner = 1;
            s.sA = 0; s.sB = 0;
            s.zAh = (long)ECAT * N;  s.zAg = (long)HH * ECAT * N;
            s.zBh = (long)KVP * N;   s.zBg = (long)HH * KVP * N;
            s.zCh = (long)ECAT * KVP; s.zCg = (long)HH * ECAT * KVP;
            s.splitH = 1; s.gx = 4; s.gy = 4; s.Z = Z; s.cfg = 0; s.blkBase = 0;
            mfma8<float, 1, 1><<<dim3(16 * Z), blk8, 0, stream>>>(J, accIt);
        }

        // softmax (stats finalize inlined); writes Sab over dead KT+Qcat
        softmax_kernel<<<dim3(ECAT, Z), dim3(256), 0, stream>>>(Sb, Sab, accIt);

        // ---- Ch on mfma8 SCHED=1 ----------------------------------------------
        {
            GemmJobs J; J.njobs = 1;
            GemmJob& c = J.j[0];
            c.A = Vb; c.B = Sab; c.C = Chb; c.alpha = 1.0f; c.cfloat = 0;
            c.lda = KVP; c.ldb = KVP; c.ldc = ECAT; c.K = KVP; c.inner = 1;
            c.sA = 0; c.sB = 0;
            c.zAh = (long)N * KVP;   c.zAg = (long)HH * N * KVP;
            c.zBh = (long)ECAT * KVP; c.zBg = (long)HH * ECAT * KVP;
            c.zCh = (long)N * ECAT;  c.zCg = (long)HH * N * ECAT;
            c.splitH = 1; c.gx = 4; c.gy = 4; c.Z = Z; c.cfg = 0; c.blkBase = 0;
            mfma8<short, 0, 1><<<dim3(16 * Z), blk8, 0, stream>>>(J, nullptr);
        }

        prevB0 = b0;
    }

    // ---- flush final O (last iteration) --------------------------------------
    {
        GemmJobs J; int nj = 0; int base = 0;
        addOJobs(J, nj, base, prevB0, G);
        J.njobs = nj;
        mfma_jt<<<dim3(base), blk, 0, stream>>>(J);
    }
}

// Round 9
// 621.304 us; speedup vs baseline: 1.0146x; 1.0146x over previous
//
#include <hip/hip_runtime.h>
#include <hip/hip_bf16.h>
#include <math.h>

#define HH    4
#define NSEQ  1024
#define KVD   960    // true KV dim
#define KVP   1024   // padded KV dim (zero pad) so every tile dim is 128-divisible
#define BATCH 8
#define ECAT  1024   // concat of branch channel dims (960 real, 64 pad rows)

static constexpr float EPS = 1e-5f;

typedef __attribute__((ext_vector_type(8))) short short8;   // 8 bf16
typedef __attribute__((ext_vector_type(4))) short short4e;  // 4 bf16
typedef __attribute__((ext_vector_type(4))) float f32x4;    // MFMA C/D frag

__device__ __forceinline__ short f2bf(float x) {
    union { __hip_bfloat16 h; short s; } u;
    u.h = __float2bfloat16(x);
    return u.s;
}
__device__ __forceinline__ short8 cvt8(const float* __restrict__ g) {
    const float4 a = *(const float4*)g;
    const float4 b = *(const float4*)(g + 4);
    short8 t;
    t[0] = f2bf(a.x); t[1] = f2bf(a.y); t[2] = f2bf(a.z); t[3] = f2bf(a.w);
    t[4] = f2bf(b.x); t[5] = f2bf(b.y); t[6] = f2bf(b.z); t[7] = f2bf(b.w);
    return t;
}

// ---- one-time input converts: 15 segments (13 plain + 2 padded-W) in ONE launch
struct ConvJobs {
    const float* src[15];
    short*       dst[15];
    long         cum[16];
    int          type[15];   // 0 = plain copy, 1 = padded WK/WV layout
    float*       statsAcc;   // zero-init side effect (block 0)
    int          nAcc;
};

__global__ void conv_all_kernel(ConvJobs J)
{
    if (blockIdx.x == 0 && threadIdx.x < (unsigned)J.nAcc)
        J.statsAcc[threadIdx.x] = 0.f;
    const long u = (long)blockIdx.x * 256 + threadIdx.x;
    if (u >= J.cum[15]) return;
    int sg = 0;
    while (u >= J.cum[sg + 1]) ++sg;
    const long l = u - J.cum[sg];
    if (J.type[sg] == 0) {
        *(short8*)(J.dst[sg] + l * 8) = cvt8(J.src[sg] + l * 8);
    } else {
        const int cpr = KVD / 8;                              // 120
        const int c8  = (int)(l % cpr) * 8;
        const int row = (int)((l / cpr) % KVP);
        const int h   = (int)(l / ((long)cpr * KVP));
        short8 t = (short8){0,0,0,0,0,0,0,0};
        if (row < KVD) t = cvt8(J.src[sg] + ((long)h * KVD + row) * KVD + c8);
        *(short8*)(J.dst[sg] + ((long)h * KVP + row) * KVD + c8) = t;
    }
}

// ---- legacy async LDS staging: ROWS x 32 bf16, 64B rows, chunk-XOR swizzle.
template<int ROWS>
__device__ __forceinline__ void stage_async(short (*dst)[32], const short* __restrict__ src,
                                            int ld, int w, int lane)
{
    #pragma unroll
    for (int p = 0; p < ROWS / 64; ++p) {
        const int rbase = p * 64 + w * 16;
        const int row   = rbase + (lane >> 2);
        const int c16l  = ((lane & 3) - row) & 3;
        const short* g  = src + (long)row * ld + c16l * 8;
        __builtin_amdgcn_global_load_lds(
            (const __attribute__((address_space(1))) void*)g,
            (__attribute__((address_space(3))) void*)&dst[rbase][0],
            16, 0, 0);
    }
}

// ---------------------------------------------------------------------------
struct GemmJob {
    const short* A; const short* B; void* C;
    float alpha;
    int lda, ldb, ldc, K, inner, gx, gy, Z, splitH, cfg, blkBase, pad0;
    long sA, sB, zAh, zAg, zBh, zBg, zCh, zCg;
};
struct GemmJobs { GemmJob j[8]; int njobs; };

// ---- legacy 128^2 GEMM body (verified): C = alpha * sum_ib A[M,K] @ B[Nc,K]^T
template<int TM, int TN, typename TC>
__device__ __forceinline__ void gemm_body(const GemmJob& job, int lb,
                                          short (*As)[32], short (*Bs)[32])
{
    constexpr int MT = TM / 32;
    constexpr int NT = TN / 32;
    const short* A = job.A;
    const short* B = job.B;
    TC* C = (TC*)job.C;
    const int bps = job.gx * job.gy;
    const int Z   = job.Z;
    int z, r;
    if ((Z & 7) == 0) {
        const int xcd = lb & 7;
        const int j   = lb >> 3;
        const int spx = Z >> 3;
        z = xcd * spx + j / bps;
        r = j % bps;
    } else {
        z = lb / bps;
        r = lb % bps;
    }
    const int x = r % job.gx, y = r / job.gx;
    int h, g;
    if (job.splitH) { h = z & (HH - 1); g = z >> 2; }
    else            { h = 0;            g = z;      }
    A += (long)h * job.zAh + (long)g * job.zAg;
    B += (long)h * job.zBh + (long)g * job.zBg;
    C += (long)h * job.zCh + (long)g * job.zCg;

    const int tid  = threadIdx.x;
    const int lane = tid & 63;
    const int w    = tid >> 6;
    const int wr   = w >> 1;
    const int wc   = w & 1;
    const int quad = lane >> 4;
    const int l16  = lane & 15;
    const long m0  = (long)y * TM;
    const long n0  = (long)x * TN;

    f32x4 acc[MT][NT];
    #pragma unroll
    for (int i = 0; i < MT; ++i)
        #pragma unroll
        for (int j2 = 0; j2 < NT; ++j2)
            acc[i][j2] = (f32x4){0.f, 0.f, 0.f, 0.f};

    for (int ib = 0; ib < job.inner; ++ib) {
        const short* Ab = A + (long)ib * job.sA + m0 * job.lda;
        const short* Bb = B + (long)ib * job.sB + n0 * job.ldb;
        for (int k0 = 0; k0 < job.K; k0 += 32) {
            stage_async<TM>(As, Ab + k0, job.lda, w, lane);
            stage_async<TN>(Bs, Bb + k0, job.ldb, w, lane);
            __syncthreads();
            short8 af[MT], bfr[NT];
            #pragma unroll
            for (int i = 0; i < MT; ++i) {
                const int rowA = wr * (TM / 2) + i * 16 + l16;
                af[i] = *(const short8*)&As[rowA][((quad + rowA) & 3) * 8];
            }
            #pragma unroll
            for (int j2 = 0; j2 < NT; ++j2) {
                const int rowB = wc * (TN / 2) + j2 * 16 + l16;
                bfr[j2] = *(const short8*)&Bs[rowB][((quad + rowB) & 3) * 8];
            }
            #pragma unroll
            for (int i = 0; i < MT; ++i)
                #pragma unroll
                for (int j2 = 0; j2 < NT; ++j2)
                    acc[i][j2] = __builtin_amdgcn_mfma_f32_16x16x32_bf16(
                        af[i], bfr[j2], acc[i][j2], 0, 0, 0);
            __syncthreads();
        }
    }

    #pragma unroll
    for (int i = 0; i < MT; ++i) {
        #pragma unroll
        for (int j2 = 0; j2 < NT; ++j2) {
            const long row = m0 + wr * (TM / 2) + i * 16 + quad * 4;
            const long col = n0 + wc * (TN / 2) + j2 * 16 + l16;
            #pragma unroll
            for (int rr = 0; rr < 4; ++rr) {
                const float v = job.alpha * acc[i][j2][rr];
                if constexpr (sizeof(TC) == 4)
                    C[(row + rr) * job.ldc + col] = v;
                else
                    C[(row + rr) * job.ldc + col] = f2bf(v);
            }
        }
    }
}

template<typename TC>
__global__ __launch_bounds__(256) void mfma_jt(GemmJobs J)
{
    __shared__ short As[128][32];
    __shared__ short Bs[128][32];
    const int bid = blockIdx.x;
    int ji = 0;
    while (ji + 1 < J.njobs && bid >= J.j[ji + 1].blkBase) ++ji;
    const GemmJob& job = J.j[ji];
    const int lb = bid - job.blkBase;
    switch (job.cfg) {
        case 0: gemm_body<128, 128, TC>(job, lb, As, Bs); break;
        case 1: gemm_body<128,  64, TC>(job, lb, As, Bs); break;
        default: gemm_body<64, 128, TC>(job, lb, As, Bs); break;
    }
}

// ---------------------------------------------------------------------------
// 256^2-tile, BK=64, 8-wave bf16 NT GEMM, counted vmcnt/lgkmcnt.
// TWO verified schedules, selected per-dispatch by measurement:
//   SCHED=0 (round-6): 4 phases/tile, B panel cached once (24 ds_reads),
//            stages ph1:(t+1)A1 ph2:(t+1)B1 ph3:(t+2)A0 ph4:(t+2)B0+vmcnt(4)
//            -> measured BEST for the mixed-NT mega1 dispatch (97.6 vs 107.4us)
//   SCHED=1 (round-7): 1 barrier-pair/tile, 24 reads up-front, lgkmcnt(8)
//            mid-barrier, MFMA(A0,B) covers A1 drain, vmcnt(4) at tile end
//            -> used for the uniform NT=16 S/Ch dispatches (best total)
// ---------------------------------------------------------------------------
#define STAGE(Pa, Pb, DST) do {                                                  \
    __builtin_amdgcn_global_load_lds(                                            \
        (const __attribute__((address_space(1))) void*)(Pa),                     \
        (__attribute__((address_space(3))) void*)(DST), 16, 0, 0);               \
    __builtin_amdgcn_global_load_lds(                                            \
        (const __attribute__((address_space(1))) void*)(Pb),                     \
        (__attribute__((address_space(3))) void*)((DST) + 4096), 16, 0, 0);      \
    (Pa) += 64; (Pb) += 64;                                                      \
} while (0)

// ---- SCHED=0 pieces (round-6) ----------------------------------------------
#define S6_BARRQ(AA, BB) do {                                                    \
    __builtin_amdgcn_s_barrier();                                                \
    asm volatile("s_waitcnt lgkmcnt(0)" ::: "memory");                           \
    __builtin_amdgcn_sched_barrier(0);                                           \
    __builtin_amdgcn_s_setprio(1);                                               \
    _Pragma("unroll")                                                            \
    for (int mi_ = 0; mi_ < 4; ++mi_)                                            \
        _Pragma("unroll")                                                        \
        for (int nj_ = 0; nj_ < 2; ++nj_) {                                      \
            acc[(AA)*4 + mi_][(BB)*2 + nj_] = __builtin_amdgcn_mfma_f32_16x16x32_bf16( \
                af_[mi_][0], bfall_[(BB)*2 + nj_][0],                            \
                acc[(AA)*4 + mi_][(BB)*2 + nj_], 0, 0, 0);                       \
            acc[(AA)*4 + mi_][(BB)*2 + nj_] = __builtin_amdgcn_mfma_f32_16x16x32_bf16( \
                af_[mi_][1], bfall_[(BB)*2 + nj_][1],                            \
                acc[(AA)*4 + mi_][(BB)*2 + nj_], 0, 0, 0);                       \
        }                                                                        \
    __builtin_amdgcn_s_setprio(0);                                               \
    __builtin_amdgcn_s_barrier();                                                \
} while (0)

#define S6_TILE(Q, T) do {                                                       \
    short8 af_[4][2], bfall_[4][2];                                              \
    _Pragma("unroll")                                                            \
    for (int mi_ = 0; mi_ < 4; ++mi_)                                            \
        _Pragma("unroll")                                                        \
        for (int ks_ = 0; ks_ < 2; ++ks_)                                        \
            af_[mi_][ks_] = *(const short8*)(paf0[mi_][ks_] + (Q)*16384);        \
    _Pragma("unroll")                                                            \
    for (int nj_ = 0; nj_ < 4; ++nj_)                                            \
        _Pragma("unroll")                                                        \
        for (int ks_ = 0; ks_ < 2; ++ks_)                                        \
            bfall_[nj_][ks_] = *(const short8*)(pbf0[nj_][ks_] + (Q)*16384);     \
    if ((T) + 1 < NT) STAGE(gA1a, gA1b, &AT[1-(Q)][1][0][0] + dofs);             \
    asm volatile("s_waitcnt lgkmcnt(8)" ::: "memory");                           \
    S6_BARRQ(0, 0);                                                              \
    if ((T) + 1 < NT) STAGE(gB1a, gB1b, &BT[1-(Q)][1][0][0] + dofs);             \
    S6_BARRQ(0, 1);                                                              \
    _Pragma("unroll")                                                            \
    for (int mi_ = 0; mi_ < 4; ++mi_)                                            \
        _Pragma("unroll")                                                        \
        for (int ks_ = 0; ks_ < 2; ++ks_)                                        \
            af_[mi_][ks_] = *(const short8*)(paf0[mi_][ks_] + (Q)*16384 + 8192); \
    if ((T) + 2 < NT) STAGE(gA0a, gA0b, &AT[(Q)][0][0][0] + dofs);               \
    S6_BARRQ(1, 0);                                                              \
    if ((T) + 2 < NT) {                                                          \
        STAGE(gB0a, gB0b, &BT[(Q)][0][0][0] + dofs);                             \
        asm volatile("s_waitcnt vmcnt(4)" ::: "memory");                         \
    } else {                                                                     \
        asm volatile("s_waitcnt vmcnt(0)" ::: "memory");                         \
    }                                                                            \
    S6_BARRQ(1, 1);                                                              \
} while (0)

// ---- SCHED=1 pieces (round-7) ----------------------------------------------
#define S7_MFMAQ(AF, AA)                                                         \
    _Pragma("unroll")                                                            \
    for (int mi_ = 0; mi_ < 4; ++mi_)                                            \
        _Pragma("unroll")                                                        \
        for (int nj_ = 0; nj_ < 4; ++nj_) {                                      \
            acc[(AA)*4 + mi_][nj_] = __builtin_amdgcn_mfma_f32_16x16x32_bf16(    \
                AF[mi_][0], ball_[nj_][0], acc[(AA)*4 + mi_][nj_], 0, 0, 0);     \
            acc[(AA)*4 + mi_][nj_] = __builtin_amdgcn_mfma_f32_16x16x32_bf16(    \
                AF[mi_][1], ball_[nj_][1], acc[(AA)*4 + mi_][nj_], 0, 0, 0);     \
        }

#define S7_TILE(Q, T) do {                                                       \
    short8 af0_[4][2], af1_[4][2], ball_[4][2];                                  \
    _Pragma("unroll")                                                            \
    for (int nj_ = 0; nj_ < 4; ++nj_)                                            \
        _Pragma("unroll")                                                        \
        for (int ks_ = 0; ks_ < 2; ++ks_)                                        \
            ball_[nj_][ks_] = *(const short8*)(pbf0[nj_][ks_] + (Q)*16384);      \
    _Pragma("unroll")                                                            \
    for (int mi_ = 0; mi_ < 4; ++mi_)                                            \
        _Pragma("unroll")                                                        \
        for (int ks_ = 0; ks_ < 2; ++ks_)                                        \
            af0_[mi_][ks_] = *(const short8*)(paf0[mi_][ks_] + (Q)*16384);       \
    _Pragma("unroll")                                                            \
    for (int mi_ = 0; mi_ < 4; ++mi_)                                            \
        _Pragma("unroll")                                                        \
        for (int ks_ = 0; ks_ < 2; ++ks_)                                        \
            af1_[mi_][ks_] = *(const short8*)(paf0[mi_][ks_] + (Q)*16384 + 8192);\
    if ((T) + 1 < NT) {                                                          \
        STAGE(gA1a, gA1b, &AT[1-(Q)][1][0][0] + dofs);                           \
        STAGE(gB1a, gB1b, &BT[1-(Q)][1][0][0] + dofs);                           \
    }                                                                            \
    asm volatile("s_waitcnt lgkmcnt(8)" ::: "memory");                           \
    __builtin_amdgcn_s_barrier();                                                \
    if ((T) + 2 < NT) {                                                          \
        STAGE(gA0a, gA0b, &AT[(Q)][0][0][0] + dofs);                             \
        STAGE(gB0a, gB0b, &BT[(Q)][0][0][0] + dofs);                             \
    }                                                                            \
    __builtin_amdgcn_sched_barrier(0);                                           \
    __builtin_amdgcn_s_setprio(1);                                               \
    S7_MFMAQ(af0_, 0);                                                           \
    __builtin_amdgcn_s_setprio(0);                                               \
    asm volatile("s_waitcnt lgkmcnt(0)" ::: "memory");                           \
    __builtin_amdgcn_sched_barrier(0);                                           \
    __builtin_amdgcn_s_setprio(1);                                               \
    S7_MFMAQ(af1_, 1);                                                           \
    __builtin_amdgcn_s_setprio(0);                                               \
    if ((T) + 2 < NT) asm volatile("s_waitcnt vmcnt(4)" ::: "memory");           \
    else              asm volatile("s_waitcnt vmcnt(0)" ::: "memory");           \
    __builtin_amdgcn_s_barrier();                                                \
} while (0)

template<typename TC, int STATS, int SCHED>
__global__ __launch_bounds__(512, 2) void mfma8(GemmJobs J, float* __restrict__ statsAcc)
{
    __shared__ short AT[2][2][128][64];
    __shared__ short BT[2][2][128][64];

    const int bid = blockIdx.x;
    int ji = 0;
    while (ji + 1 < J.njobs && bid >= J.j[ji + 1].blkBase) ++ji;
    const GemmJob& job = J.j[ji];
    const int lb = bid - job.blkBase;
    const int Z  = job.Z;
    const int gx = job.gx;
    const int bps = gx * job.gy;
    int z, r;
    if ((Z & 7) == 0) {
        const int xcd = lb & 7;
        const int jj  = lb >> 3;
        const int spx = Z >> 3;
        z = xcd * spx + jj / bps;
        r = jj % bps;
    } else {
        z = lb / bps;
        r = lb % bps;
    }
    const int x = r % gx, y = r / gx;
    int h, g;
    if (job.splitH) { h = z & (HH - 1); g = z >> 2; }
    else            { h = 0;            g = z;      }
    const int lda = job.lda, ldb = job.ldb, ldc = job.ldc;
    const short* A = job.A + (long)h * job.zAh + (long)g * job.zAg + (long)(y * 256) * lda;
    const short* B = job.B + (long)h * job.zBh + (long)g * job.zBg + (long)(x * 256) * ldb;
    TC* C = (TC*)job.C + (long)h * job.zCh + (long)g * job.zCg;
    const int NT = job.K >> 6;

    const int tid  = threadIdx.x;
    const int lane = tid & 63;
    const int w    = tid >> 6;
    const int wm   = w >> 2;        // 0..1
    const int wn   = w & 3;         // 0..3
    const int quad = lane >> 4;
    const int l16  = lane & 15;
    const int dofs = w * 512;       // LDS short-offset of this wave's 1KB stage slot

    // global stage pointers (per-lane, chunk-rotation pre-swizzled [m104/m173])
    const int o16 = w * 64 + lane;
    const int rS  = o16 >> 3;
    const int pcS = o16 & 7;
    const int lcS = ((pcS - rS) & 7) * 8;
    const short* gA0a = A + (long)rS * lda + lcS;
    const short* gA0b = A + (long)(rS + 64) * lda + lcS;
    const short* gA1a = gA0a + 128 * lda;
    const short* gA1b = gA0b + 128 * lda;
    const short* gB0a = B + (long)rS * ldb + lcS;
    const short* gB0b = B + (long)(rS + 64) * ldb + lcS;
    const short* gB1a = gB0a + 128 * ldb;
    const short* gB1b = gB0b + 128 * ldb;

    // hoisted LDS fragment base addresses (q=0; A at half0, B covers both halves)
    const short* paf0[4][2];
    #pragma unroll
    for (int mi = 0; mi < 4; ++mi)
        #pragma unroll
        for (int ks = 0; ks < 2; ++ks) {
            const int rr = mi * 32 + wm * 16 + l16;
            paf0[mi][ks] = &AT[0][0][rr][((ks * 4 + quad + rr) & 7) * 8];
        }
    const short* pbf0[4][2];
    #pragma unroll
    for (int nj = 0; nj < 4; ++nj)
        #pragma unroll
        for (int ks = 0; ks < 2; ++ks) {
            const int r2 = (nj & 1) * 64 + wn * 16 + l16;
            pbf0[nj][ks] = &BT[0][nj >> 1][r2][((ks * 4 + quad + r2) & 7) * 8];
        }

    f32x4 acc[8][4];
    #pragma unroll
    for (int i = 0; i < 8; ++i)
        #pragma unroll
        for (int j2 = 0; j2 < 4; ++j2)
            acc[i][j2] = (f32x4){0.f, 0.f, 0.f, 0.f};

    // prologue: tile0 all 4 halves + tile1 A0/B0; drain tile0, keep tile1 in flight
    STAGE(gA0a, gA0b, &AT[0][0][0][0] + dofs);
    STAGE(gA1a, gA1b, &AT[0][1][0][0] + dofs);
    STAGE(gB0a, gB0b, &BT[0][0][0][0] + dofs);
    STAGE(gB1a, gB1b, &BT[0][1][0][0] + dofs);
    STAGE(gA0a, gA0b, &AT[1][0][0][0] + dofs);   // NT >= 4 in all uses
    STAGE(gB0a, gB0b, &BT[1][0][0][0] + dofs);
    asm volatile("s_waitcnt vmcnt(4)" ::: "memory");
    __builtin_amdgcn_s_barrier();

    const int NPAIR = NT >> 1;
    if constexpr (SCHED == 0) {
        for (int tt = 0; tt < NPAIR; ++tt) {
            S6_TILE(0, tt * 2);
            S6_TILE(1, tt * 2 + 1);
        }
        if (NT & 1) S6_TILE(0, NT - 1);
    } else {
        for (int tt = 0; tt < NPAIR; ++tt) {
            S7_TILE(0, tt * 2);
            S7_TILE(1, tt * 2 + 1);
        }
        if (NT & 1) S7_TILE(0, NT - 1);
    }

    // epilogue: C/D layout col=lane&15, row=(lane>>4)*4+reg [m89-verified]
    float s0 = 0.f, ss0 = 0.f, s1 = 0.f, ss1 = 0.f;   // buckets: rows<896, rows 896..959
    #pragma unroll
    for (int mi = 0; mi < 8; ++mi) {
        #pragma unroll
        for (int nj = 0; nj < 4; ++nj) {
            const long row = (long)y * 256 + mi * 32 + wm * 16 + quad * 4;
            const long col = (long)x * 256 + nj * 64 + wn * 16 + l16;
            #pragma unroll
            for (int rr = 0; rr < 4; ++rr) {
                const float v = job.alpha * acc[mi][nj][rr];
                if constexpr (sizeof(TC) == 4)
                    C[(row + rr) * ldc + col] = v;
                else
                    C[(row + rr) * ldc + col] = f2bf(v);
                if constexpr (STATS) {
                    const long gr = row + rr;
                    if (gr < 896)          { s0 += v; ss0 += v * v; }
                    else if (gr < KVD)     { s1 += v; ss1 += v * v; }
                }
            }
        }
    }
    if constexpr (STATS) {
        __syncthreads();
        float* red = (float*)&AT[0][0][0][0];
        red[tid] = s0; red[512 + tid] = ss0; red[1024 + tid] = s1; red[1536 + tid] = ss1;
        __syncthreads();
        for (int o = 256; o > 0; o >>= 1) {
            if (tid < o) {
                red[tid]        += red[tid + o];
                red[512 + tid]  += red[512 + tid + o];
                red[1024 + tid] += red[1024 + tid + o];
                red[1536 + tid] += red[1536 + tid + o];
            }
            __syncthreads();
        }
        if (tid == 0) {
            const int m0g = y * 256;
            const int bA = (m0g >= 768) ? 1 : (m0g >= 512) ? 2 : 3;
            atomicAdd(&statsAcc[((long)z * 4 + bA) * 2],     red[0]);
            atomicAdd(&statsAcc[((long)z * 4 + bA) * 2 + 1], red[512]);
            if (y == 3) {   // rows 896..959 -> branch 0 (df=64)
                atomicAdd(&statsAcc[((long)z * 4 + 0) * 2],     red[1024]);
                atomicAdd(&statsAcc[((long)z * 4 + 0) * 2 + 1], red[1536]);
            }
        }
    }
}

// ---- softmax over real 960 cols; stats finalize inlined (reads atomic sums).
__global__ void softmax_kernel(const float* __restrict__ S,
                               short* __restrict__ Sa,
                               const float* __restrict__ acc)
{
    const int row = blockIdx.x;          // 0..1023 concat rows (>=960 = pad)
    const int y   = blockIdx.y;
    const int t   = threadIdx.x;
    short* orow = Sa + ((long)y * ECAT + row) * KVP;
    if (row >= KVD) {                    // zero pad row (clean B-operand for Ch)
        *(short4e*)(orow + 4 * t) = (short4e){0, 0, 0, 0};
        return;
    }
    const int bidx = (row >= 896) ? 0 : (row >= 768) ? 1 : (row >= 512) ? 2 : 3;
    const int dftab[4] = {64, 128, 256, 512};
    const float sum0 = acc[((long)y * 4 + bidx) * 2];
    const float ssq0 = acc[((long)y * 4 + bidx) * 2 + 1];
    const float n    = (float)(dftab[bidx] * KVD);
    const float mean = sum0 / n;
    const float rstd = rsqrtf(ssq0 / n - mean * mean + EPS);
    const float* srow = S + ((long)y * ECAT + row) * KVP;

    const bool real = (t < KVD / 4);     // threads 0..239 hold real cols (4 each)
    float x[4];
    float mx = -1e30f;
    if (real) {
        const float4 v = *(const float4*)(srow + 4 * t);
        x[0] = (v.x - mean) * rstd; x[1] = (v.y - mean) * rstd;
        x[2] = (v.z - mean) * rstd; x[3] = (v.w - mean) * rstd;
        mx = fmaxf(fmaxf(x[0], x[1]), fmaxf(x[2], x[3]));
    }
    __shared__ float red[256];
    red[t] = mx; __syncthreads();
    for (int o = 128; o > 0; o >>= 1) {
        if (t < o) red[t] = fmaxf(red[t], red[t + o]);
        __syncthreads();
    }
    mx = red[0];
    __syncthreads();

    float e[4] = {0.f, 0.f, 0.f, 0.f};
    float sum = 0.f;
    if (real) {
        e[0] = __expf(x[0] - mx); e[1] = __expf(x[1] - mx);
        e[2] = __expf(x[2] - mx); e[3] = __expf(x[3] - mx);
        sum = e[0] + e[1] + e[2] + e[3];
    }
    red[t] = sum; __syncthreads();
    for (int o = 128; o > 0; o >>= 1) {
        if (t < o) red[t] += red[t + o];
        __syncthreads();
    }
    const float inv = 1.0f / red[0];
    short4e o4;
    o4[0] = f2bf(e[0] * inv); o4[1] = f2bf(e[1] * inv);
    o4[2] = f2bf(e[2] * inv); o4[3] = f2bf(e[3] * inv);
    *(short4e*)(orow + 4 * t) = o4;
}

// ---------------------------------------------------------------------------
extern "C" void kernel_launch(void* const* d_in, const int* in_sizes, int n_in,
                              void* d_out, int out_size, void* d_ws, size_t ws_size,
                              hipStream_t stream)
{
    (void)in_sizes; (void)n_in; (void)out_size;
    const float* emb[4]  = {(const float*)d_in[0], (const float*)d_in[1],
                            (const float*)d_in[2], (const float*)d_in[3]};
    const float* emb_all = (const float*)d_in[4];
    const float* WQ[4]   = {(const float*)d_in[5], (const float*)d_in[6],
                            (const float*)d_in[7], (const float*)d_in[8]};
    const float* WK      = (const float*)d_in[9];
    const float* WV      = (const float*)d_in[10];
    const float* WO[4]   = {(const float*)d_in[11], (const float*)d_in[12],
                            (const float*)d_in[13], (const float*)d_in[14]};
    float* out = (float*)d_out;

    const int dfs[4]    = {64, 128, 256, 512};
    const int rowoff[4] = {896, 768, 512, 0};   // concat offsets (tile-aligned)
    const long N = NSEQ;

    // ---- workspace budget (Sacat aliases KT+Qcat; Chcat aliases Scat)
    const long eAll = (long)BATCH * N * KVD;
    const long eWKp = (long)HH * KVP * KVD;
    long preBytes = eAll * 2 + 2 * eWKp * 2;
    for (int br = 0; br < 4; ++br)
        preBytes += ((long)BATCH * N * dfs[br] + (long)HH * dfs[br] * dfs[br]
                    + (long)dfs[br] * dfs[br]) * 2;
    const long perG = (long)HH * KVP * N * 2
                    + (long)HH * ECAT * N * 2
                    + (long)HH * N * KVP * 2
                    + (long)HH * ECAT * KVP * 4;
    int G = 8;
    while (G > 1 && preBytes + (long)G * perG + 65536 > (long)ws_size) G >>= 1;

    // ---- carve workspace (KTb and Qb contiguous: Sab aliases their union)
    char* p = (char*)d_ws;
    short* embAllp = (short*)p; p += eAll * 2;
    short* embp[4]; short* WQp[4]; short* WOp[4];
    for (int br = 0; br < 4; ++br) { embp[br] = (short*)p; p += (long)BATCH * N * dfs[br] * 2; }
    for (int br = 0; br < 4; ++br) { WQp[br]  = (short*)p; p += (long)HH * dfs[br] * dfs[br] * 2; }
    short* WKp = (short*)p; p += eWKp * 2;
    short* WVp = (short*)p; p += eWKp * 2;
    for (int br = 0; br < 4; ++br) { WOp[br]  = (short*)p; p += (long)dfs[br] * dfs[br] * 2; }
    short* KTb = (short*)p; p += (long)G * HH * KVP * N * 2;
    short* Qb  = (short*)p; p += (long)G * HH * ECAT * N * 2;    // Qcat
    short* Vb  = (short*)p; p += (long)G * HH * N * KVP * 2;
    float* Sb  = (float*)p; p += (long)G * HH * ECAT * KVP * 4;  // Scat
    float* statsAcc = (float*)p; p += (long)BATCH * HH * 4 * 2 * 4;
    short* Sab = (short*)KTb;  // Sacat aliases KT+Qcat (dead after S GEMM)
    short* Chb = (short*)Sb;   // Chcat aliases Scat (dead after softmax)

    // ---- ONE convert launch: 13 plain segments + 2 padded-W segments
    {
        ConvJobs J;
        long cum = 0; int sg = 0;
        auto addJob = [&](const float* src, short* dst, long nunits, int ty) {
            J.src[sg] = src; J.dst[sg] = dst; J.cum[sg] = cum; J.type[sg] = ty;
            cum += nunits; ++sg;
        };
        addJob(emb_all, embAllp, eAll / 8, 0);
        for (int br = 0; br < 4; ++br) addJob(emb[br], embp[br], (long)BATCH * N * dfs[br] / 8, 0);
        for (int br = 0; br < 4; ++br) addJob(WQ[br], WQp[br], (long)HH * dfs[br] * dfs[br] / 8, 0);
        for (int br = 0; br < 4; ++br) addJob(WO[br], WOp[br], (long)dfs[br] * dfs[br] / 8, 0);
        addJob(WK, WKp, (long)HH * KVP * (KVD / 8), 1);
        addJob(WV, WVp, (long)HH * KVP * (KVD / 8), 1);
        J.cum[15] = cum;
        J.statsAcc = statsAcc;
        J.nAcc = BATCH * HH * 4 * 2;
        conv_all_kernel<<<dim3((unsigned)((cum + 255) / 256)), dim3(256), 0, stream>>>(J);
    }

    const float scale = 1.0f / sqrtf((float)KVD);
    long outBase[4];
    {
        long acc = 0;
        for (int br = 0; br < 4; ++br) { outBase[br] = acc; acc += (long)BATCH * N * dfs[br]; }
    }

    const dim3 blk(256), blk8(512);
    int it = 0;
    for (int b0 = 0; b0 < BATCH; b0 += G, ++it) {
        const int Z = G * HH;
        const short* embA = embAllp + (long)b0 * N * KVD;
        float* accIt = statsAcc + (long)it * Z * 4 * 2;

        // ---- mega1 on mfma8 SCHED=0: KT + V + Q512 + Q256 ---------------------
        {
            GemmJobs J; int nj = 0; int base = 0;
            auto add8 = [&](const short* A, const short* B, void* C, float alpha,
                            int lda, int ldb, int ldc, int K,
                            long zAh, long zAg, long zBh, long zBg,
                            long zCh, long zCg, int gx, int gy) {
                GemmJob& q = J.j[nj];
                q.A = A; q.B = B; q.C = C; q.alpha = alpha;
                q.lda = lda; q.ldb = ldb; q.ldc = ldc; q.K = K; q.inner = 1;
                q.sA = 0; q.sB = 0;
                q.zAh = zAh; q.zAg = zAg; q.zBh = zBh; q.zBg = zBg;
                q.zCh = zCh; q.zCg = zCg;
                q.splitH = 1; q.gx = gx; q.gy = gy; q.Z = Z; q.cfg = 0;
                q.blkBase = base;
                base += gx * gy * Z; ++nj;
            };
            add8(WKp, embA, KTb, 1.0f, KVD, KVD, (int)N, KVD,
                 (long)KVP * KVD, 0, 0, (long)N * KVD,
                 (long)KVP * N, (long)HH * KVP * N, 4, 4);
            add8(embA, WVp, Vb, 1.0f, KVD, KVD, KVP, KVD,
                 0, (long)N * KVD, (long)KVP * KVD, 0,
                 (long)N * KVP, (long)HH * N * KVP, 4, 4);
            add8(WQp[3], embp[3] + (long)b0 * N * 512, Qb + (long)rowoff[3] * N, 1.0f,
                 512, 512, (int)N, 512,
                 512L * 512, 0, 0, (long)N * 512,
                 (long)ECAT * N, (long)HH * ECAT * N, 4, 2);
            add8(WQp[2], embp[2] + (long)b0 * N * 256, Qb + (long)rowoff[2] * N, 1.0f,
                 256, 256, (int)N, 256,
                 256L * 256, 0, 0, (long)N * 256,
                 (long)ECAT * N, (long)HH * ECAT * N, 4, 1);
            J.njobs = nj;
            mfma8<short, 0, 0><<<dim3(base), blk8, 0, stream>>>(J, nullptr);
        }

        // ---- Q128 + Q64 (legacy job-table) -> concat rows of Qcat -------------
        {
            GemmJobs J; int nj = 0; int base = 0;
            for (int br = 1; br >= 0; --br) {
                const int df = dfs[br];
                GemmJob& q = J.j[nj];
                q.A = WQp[br]; q.B = embp[br] + (long)b0 * N * df;
                q.C = Qb + (long)rowoff[br] * N;
                q.alpha = 1.0f;
                q.lda = df; q.ldb = df; q.ldc = (int)N; q.K = df; q.inner = 1;
                q.sA = 0; q.sB = 0;
                q.zAh = (long)df * df; q.zAg = 0;
                q.zBh = 0;             q.zBg = (long)N * df;
                q.zCh = (long)ECAT * N; q.zCg = (long)HH * ECAT * N;
                q.splitH = 1; q.Z = Z; q.gx = 8; q.gy = 1;
                q.cfg = (df >= 128) ? 0 : 2;
                q.blkBase = base;
                base += 8 * Z;
                ++nj;
            }
            J.njobs = nj;
            mfma_jt<short><<<dim3(base), blk, 0, stream>>>(J);
        }

        // ---- S on mfma8 SCHED=1 (fused instance-norm stats) -------------------
        {
            GemmJobs J; J.njobs = 1;
            GemmJob& s = J.j[0];
            s.A = Qb; s.B = KTb; s.C = Sb; s.alpha = scale;
            s.lda = (int)N; s.ldb = (int)N; s.ldc = KVP; s.K = (int)N; s.inner = 1;
            s.sA = 0; s.sB = 0;
            s.zAh = (long)ECAT * N;  s.zAg = (long)HH * ECAT * N;
            s.zBh = (long)KVP * N;   s.zBg = (long)HH * KVP * N;
            s.zCh = (long)ECAT * KVP; s.zCg = (long)HH * ECAT * KVP;
            s.splitH = 1; s.gx = 4; s.gy = 4; s.Z = Z; s.cfg = 0; s.blkBase = 0;
            mfma8<float, 1, 1><<<dim3(16 * Z), blk8, 0, stream>>>(J, accIt);
        }

        // softmax (stats finalize inlined); writes Sab over dead KT+Qcat
        softmax_kernel<<<dim3(ECAT, Z), dim3(256), 0, stream>>>(Sb, Sab, accIt);

        // ---- Ch on mfma8 SCHED=1 ----------------------------------------------
        {
            GemmJobs J; J.njobs = 1;
            GemmJob& c = J.j[0];
            c.A = Vb; c.B = Sab; c.C = Chb; c.alpha = 1.0f;
            c.lda = KVP; c.ldb = KVP; c.ldc = ECAT; c.K = KVP; c.inner = 1;
            c.sA = 0; c.sB = 0;
            c.zAh = (long)N * KVP;   c.zAg = (long)HH * N * KVP;
            c.zBh = (long)ECAT * KVP; c.zBg = (long)HH * ECAT * KVP;
            c.zCh = (long)N * ECAT;  c.zCg = (long)HH * N * ECAT;
            c.splitH = 1; c.gx = 4; c.gy = 4; c.Z = Z; c.cfg = 0; c.blkBase = 0;
            mfma8<short, 0, 1><<<dim3(16 * Z), blk8, 0, stream>>>(J, nullptr);
        }

        // ---- O mega-launch: 4 branches, one job table (legacy, typed f32) -----
        {
            GemmJobs J; int nj = 0; int base = 0;
            for (int br = 3; br >= 0; --br) {
                const int df = dfs[br];
                GemmJob& q = J.j[nj];
                q.A = Chb + rowoff[br]; q.B = WOp[br];
                q.C = out + outBase[br] + (long)b0 * N * df;
                q.alpha = 1.0f / HH;
                q.lda = ECAT; q.ldb = df; q.ldc = df; q.K = df; q.inner = HH;
                q.sA = (long)N * ECAT; q.sB = 0;
                q.zAh = 0; q.zAg = (long)HH * N * ECAT; q.zBh = 0; q.zBg = 0;
                q.zCh = 0; q.zCg = (long)N * df;
                q.splitH = 0; q.Z = G; q.gy = 8;
                if (df >= 128) { q.cfg = 0; q.gx = df / 128; }
                else           { q.cfg = 1; q.gx = 1;        }
                q.blkBase = base;
                base += q.gx * q.gy * G;
                ++nj;
            }
            J.njobs = nj;
            mfma_jt<float><<<dim3(base), blk, 0, stream>>>(J);
        }
    }
}